// Round 12
// baseline (274.038 us; speedup 1.0000x reference)
//
#include <hip/hip_runtime.h>
#include <math.h>

// MADE autoregressive sampler, incremental-by-degree, v11 (= v9 + spill fix).
// B=8192, D=64, CTX=256, H=512. Units sorted by degree (mh = h%63+1).
// Structure: Rn=8 rows/block, 256 threads, 2 units/thread, 3 barriers/step,
// consumer-packed weights Wq[i][q][12] / Woq[i][j][20], f2 packed math.
// v11 vs v9: __launch_bounds__(256,2) instead of (256,4). Evidence across
// rounds: min-waves>=4 (v9: VGPR 64, 4MB scratch; v10: 56, 30MB) makes the
// allocator clamp registers and spill; min-waves=2 lands 84-96 VGPR with
// zero spill (v5/v6/v8). Grid is 1024 blocks -> 4 blocks/CU regardless.

typedef float f2 __attribute__((ext_vector_type(2)));

#define Bn 8192
#define Dn 64
#define CTXn 256
#define Hn 512
#define On 128
#define Rn 8

#define WQ_SZ  (64 * 512 * 12)   // 393216
#define WOQ_SZ (64 * 64 * 20)    //  81920
#define WCP_SZ (CTXn * Hn)       // 131072

// sorted index p -> original hidden unit h, and its degree k.
__device__ __forceinline__ int perm_of(int p, int* degout) {
  int k, t;
  if (p < 72) { k = p / 9 + 1; t = p - (k - 1) * 9; }
  else        { int pp = p - 72; k = pp / 8 + 9; t = pp - (k - 9) * 8; }
  *degout = k;
  return (k - 1) + 63 * t;
}

// ---------------- prep ------------------------------------------------------
// Wq[i][q][e]: e<9 -> W2 from group-i unit e into q (M2, zero-padded);
//              e==9 -> W1 col i into q (M1 incl diagonal); e=10,11 pad.
// Woq[i][j][e]: e<9 -> Wog p=e -> col j; e==9 pad; 10..18 -> p=e-10, col j+64;
//              e==19 pad. (Mo: col-final mask j >= i+1.)
__global__ void prep_kernel(const float* __restrict__ W1, const float* __restrict__ Wc,
                            const float* __restrict__ W2, const float* __restrict__ Wo,
                            const float* __restrict__ b1, const float* __restrict__ b2,
                            float* __restrict__ Wq, float* __restrict__ Woq,
                            float* __restrict__ WcpT, float* __restrict__ b1p,
                            float* __restrict__ b2p) {
  int idx = blockIdx.x * 256 + threadIdx.x;
  if (idx < WQ_SZ) {
    int i = idx / 6144, rem = idx - i * 6144;
    int q = rem / 12, e = rem - q * 12;
    int sb = (i < 8) ? 9 * i : 8 * i + 8;          // S_of(i+1)
    int c  = (i == 63) ? 0 : ((i < 8) ? 9 : 8);
    int dq; int hq = perm_of(q, &dq);
    float v = 0.f;
    if (e < 9) {
      if (e < c && dq >= i + 1) {                  // M2: deg_out >= i+1
        int dp; int hp = perm_of(sb + e, &dp);
        v = W2[hq * Hn + hp];
      }
    } else if (e == 9) {
      if (dq >= i + 1) v = W1[hq * Dn + i];        // M1 incl diagonal
    }
    Wq[idx] = v;
  } else if (idx < WQ_SZ + WOQ_SZ) {
    int jj = idx - WQ_SZ;
    int i = jj / 1280, rem = jj - i * 1280;
    int j = rem / 20, e = rem - j * 20;
    int sb = (i < 8) ? 9 * i : 8 * i + 8;
    int c  = (i == 63) ? 0 : ((i < 8) ? 9 : 8);
    float v = 0.f;
    int p = -1, o = 0;
    if (e < 9)                  { p = e;      o = j; }
    else if (e >= 10 && e < 19) { p = e - 10; o = j + 64; }
    if (p >= 0 && p < c && j >= i + 1) {           // Mo: (o&63) >= i+1
      int dp; int hp = perm_of(sb + p, &dp);
      v = Wo[o * Hn + hp];
    }
    Woq[jj] = v;
  } else if (idx < WQ_SZ + WOQ_SZ + WCP_SZ) {
    int jj = idx - (WQ_SZ + WOQ_SZ);
    int cc = jj >> 9, q = jj & 511;
    int dq; int hq = perm_of(q, &dq);
    WcpT[jj] = Wc[hq * CTXn + cc];
  } else if (idx < WQ_SZ + WOQ_SZ + WCP_SZ + 512) {
    int q = idx - (WQ_SZ + WOQ_SZ + WCP_SZ);
    int dq; int hq = perm_of(q, &dq);
    b1p[q] = b1[hq];
  } else if (idx < WQ_SZ + WOQ_SZ + WCP_SZ + 1024) {
    int q = idx - (WQ_SZ + WOQ_SZ + WCP_SZ + 512);
    int dq; int hq = perm_of(q, &dq);
    b2p[q] = b2[hq];
  }
}

// ---------------- main fused kernel ------------------------------------------
__global__ __launch_bounds__(256, 2)
void made_pk_kernel(
    const float* __restrict__ context, const float* __restrict__ WcpT,
    const float* __restrict__ b1p,
    const float* __restrict__ Wq, const float* __restrict__ Woq,
    const float* __restrict__ b2p, const float* __restrict__ bo,
    const float* __restrict__ eps, float* __restrict__ out) {
  __shared__ __align__(16) float ctxR[8][264];
  __shared__ __align__(16) float zcur[8];
  __shared__ __align__(16) float h1g[9][8];
  __shared__ __align__(16) float h2g[9][8];

  int t = threadIdx.x;
  int b0 = blockIdx.x * Rn;
  int rp = t >> 6, l = t & 63;           // wave rp owns rows 2rp, 2rp+1; col-pair l
  int q0 = t, q1 = t + 256;              // owned sorted units

  int g0 = ((q0 < 72) ? q0 / 9 + 1 : (q0 - 72) / 8 + 9) - 1;   // finalize steps
  int g1 = ((q1 - 72) / 8 + 9) - 1;
  int qm = t | 63;                        // wave-uniform max index
  int gm0s = __builtin_amdgcn_readfirstlane(
      ((qm < 72) ? qm / 9 + 1 : (qm - 72) / 8 + 9) - 1);
  int gm1s = __builtin_amdgcn_readfirstlane(((qm + 256 - 72) / 8 + 9) - 1);

  // ---- stage ctx ----
  #pragma unroll
  for (int r = 0; r < 8; ++r)
    ctxR[r][t] = context[(b0 + r) * CTXn + t];
  __syncthreads();

  // ---- ctx GEMM (v6-proven) ----
  float acc0[8], acc1[8];
  {
    float bias0 = b1p[q0], bias1 = b1p[q1];
    #pragma unroll
    for (int r = 0; r < 8; ++r) { acc0[r] = bias0; acc1[r] = bias1; }
  }
  {
    const float* wc = WcpT;
    #pragma clang loop unroll(disable)
    for (int c4 = 0; c4 < CTXn / 4; ++c4) {
      float xr[8][4];
      #pragma unroll
      for (int r = 0; r < 8; ++r) {
        float4 x = *(const float4*)&ctxR[r][4 * c4];
        xr[r][0] = x.x; xr[r][1] = x.y; xr[r][2] = x.z; xr[r][3] = x.w;
      }
      #pragma unroll
      for (int k = 0; k < 4; ++k) {
        float w0 = wc[q0], w1 = wc[q1];
        #pragma unroll
        for (int r = 0; r < 8; ++r) {
          acc0[r] = fmaf(xr[r][k], w0, acc0[r]);
          acc1[r] = fmaf(xr[r][k], w1, acc1[r]);
        }
        wc += Hn;
      }
    }
  }

  // ---- pack state into float2 row-pairs ----
  f2 a10[4], a11[4], a20[4], a21[4];
  #pragma unroll
  for (int r2 = 0; r2 < 4; ++r2) {
    a10[r2] = (f2){acc0[2 * r2], acc0[2 * r2 + 1]};
    a11[r2] = (f2){acc1[2 * r2], acc1[2 * r2 + 1]};
  }
  {
    float bb0 = b2p[q0], bb1 = b2p[q1];
    #pragma unroll
    for (int r2 = 0; r2 < 4; ++r2) {
      a20[r2] = (f2){bb0, bb0};
      a21[r2] = (f2){bb1, bb1};
    }
  }
  f2 ocA = (f2){bo[l], bo[l]};           // col l, rows (2rp, 2rp+1)
  f2 ocB = (f2){bo[l + 64], bo[l + 64]};
  f2 ez2 = (f2){eps[(b0 + 2 * rp) * Dn + l], eps[(b0 + 2 * rp + 1) * Dn + l]};
  f2 zs = (f2){0.f, 0.f}, mus = zs, scs = zs;

  const float* wq0p = Wq + (size_t)q0 * 12;
  const float* wq1p = Wq + (size_t)q1 * 12;
  const float* wopp = Woq + (size_t)l * 20;

  // ---- sequential loop: 3 barriers/step (must stay rolled) ----
  #pragma clang loop unroll(disable)
  for (int i = 0; i < Dn; ++i) {
    // E: this thread's cols (l, l+64) final when l == i (oacc through D(i-1))
    if (l == i) {
      f2 pre = ocB;
      float sx = fmaxf(pre.x, 0.f) + __logf(1.f + __expf(-fabsf(pre.x)));
      float sy = fmaxf(pre.y, 0.f) + __logf(1.f + __expf(-fabsf(pre.y)));
      f2 sc = (f2){sx, sy};
      f2 z = ocA + sc * ez2;
      *(f2*)&zcur[2 * rp] = z;
      zs = z; mus = ocA; scs = sc;
    }
    __syncthreads();                               // bar1: z published

    int sb = (i < 8) ? 9 * i : 8 * i + 8;          // group-i base
    bool liveB = (i <= gm1s);                      // wave-uniform
    bool liveA = (i <= gm0s);
    float4 A1c0, A1c1, A1c2, A0c0, A0c1, A0c2;
    if (liveB) {
      const float4* a4 = (const float4*)wq1p;      // 3 b128, imm offsets
      A1c0 = a4[0]; A1c1 = a4[1]; A1c2 = a4[2];
      if (liveA) {
        const float4* b4 = (const float4*)wq0p;
        A0c0 = b4[0]; A0c1 = b4[1]; A0c2 = b4[2];
      }
      float4 za = *(const float4*)&zcur[0];
      float4 zb = *(const float4*)&zcur[4];
      f2 zc0 = (f2){za.x, za.y}, zc1 = (f2){za.z, za.w};
      f2 zc2 = (f2){zb.x, zb.y}, zc3 = (f2){zb.z, zb.w};
      // FA unit1: a1 += z_i * W1 (slot [9] = chunk2.y), publish if finalizing
      {
        f2 wv = (f2){A1c2.y, A1c2.y};
        a11[0] += wv * zc0; a11[1] += wv * zc1;
        a11[2] += wv * zc2; a11[3] += wv * zc3;
        if (g1 == i) {
          int pp = q1 - sb;
          float4 h0 = {fmaxf(a11[0].x, 0.f), fmaxf(a11[0].y, 0.f),
                       fmaxf(a11[1].x, 0.f), fmaxf(a11[1].y, 0.f)};
          float4 h1_ = {fmaxf(a11[2].x, 0.f), fmaxf(a11[2].y, 0.f),
                        fmaxf(a11[3].x, 0.f), fmaxf(a11[3].y, 0.f)};
          *(float4*)&h1g[pp][0] = h0; *(float4*)&h1g[pp][4] = h1_;
        }
      }
      if (liveA) {
        f2 wv = (f2){A0c2.y, A0c2.y};
        a10[0] += wv * zc0; a10[1] += wv * zc1;
        a10[2] += wv * zc2; a10[3] += wv * zc3;
        if (g0 == i) {
          int pp = q0 - sb;
          float4 h0 = {fmaxf(a10[0].x, 0.f), fmaxf(a10[0].y, 0.f),
                       fmaxf(a10[1].x, 0.f), fmaxf(a10[1].y, 0.f)};
          float4 h1_ = {fmaxf(a10[2].x, 0.f), fmaxf(a10[2].y, 0.f),
                        fmaxf(a10[3].x, 0.f), fmaxf(a10[3].y, 0.f)};
          *(float4*)&h1g[pp][0] = h0; *(float4*)&h1g[pp][4] = h1_;
        }
      }
    }
    __syncthreads();                               // bar2: h1 published

    // Woq prefetch (used in D after bar3 -> drains at an anyway-barrier)
    const float4* w4 = (const float4*)wopp;
    float4 B0 = w4[0], B1 = w4[1], B2 = w4[2], B3 = w4[3], B4 = w4[4];

    if (liveB) {
      float wA1[9] = {A1c0.x, A1c0.y, A1c0.z, A1c0.w,
                      A1c1.x, A1c1.y, A1c1.z, A1c1.w, A1c2.x};
      if (liveA) {
        float wA0[9] = {A0c0.x, A0c0.y, A0c0.z, A0c0.w,
                        A0c1.x, A0c1.y, A0c1.z, A0c1.w, A0c2.x};
        #pragma unroll
        for (int p = 0; p < 9; ++p) {
          float4 ha = *(const float4*)&h1g[p][0];
          float4 hb = *(const float4*)&h1g[p][4];
          f2 h0 = (f2){ha.x, ha.y}, h1_ = (f2){ha.z, ha.w};
          f2 h2_ = (f2){hb.x, hb.y}, h3 = (f2){hb.z, hb.w};
          f2 wv1 = (f2){wA1[p], wA1[p]};
          f2 wv0 = (f2){wA0[p], wA0[p]};
          a21[0] += wv1 * h0; a21[1] += wv1 * h1_;
          a21[2] += wv1 * h2_; a21[3] += wv1 * h3;
          a20[0] += wv0 * h0; a20[1] += wv0 * h1_;
          a20[2] += wv0 * h2_; a20[3] += wv0 * h3;
        }
      } else {
        #pragma unroll
        for (int p = 0; p < 9; ++p) {
          float4 ha = *(const float4*)&h1g[p][0];
          float4 hb = *(const float4*)&h1g[p][4];
          f2 h0 = (f2){ha.x, ha.y}, h1_ = (f2){ha.z, ha.w};
          f2 h2_ = (f2){hb.x, hb.y}, h3 = (f2){hb.z, hb.w};
          f2 wv1 = (f2){wA1[p], wA1[p]};
          a21[0] += wv1 * h0; a21[1] += wv1 * h1_;
          a21[2] += wv1 * h2_; a21[3] += wv1 * h3;
        }
      }
      if (g1 == i) {
        int pp = q1 - sb;
        float4 h0 = {fmaxf(a21[0].x, 0.f), fmaxf(a21[0].y, 0.f),
                     fmaxf(a21[1].x, 0.f), fmaxf(a21[1].y, 0.f)};
        float4 h1_ = {fmaxf(a21[2].x, 0.f), fmaxf(a21[2].y, 0.f),
                      fmaxf(a21[3].x, 0.f), fmaxf(a21[3].y, 0.f)};
        *(float4*)&h2g[pp][0] = h0; *(float4*)&h2g[pp][4] = h1_;
      }
      if (liveA && g0 == i) {
        int pp = q0 - sb;
        float4 h0 = {fmaxf(a20[0].x, 0.f), fmaxf(a20[0].y, 0.f),
                     fmaxf(a20[1].x, 0.f), fmaxf(a20[1].y, 0.f)};
        float4 h1_ = {fmaxf(a20[2].x, 0.f), fmaxf(a20[2].y, 0.f),
                      fmaxf(a20[3].x, 0.f), fmaxf(a20[3].y, 0.f)};
        *(float4*)&h2g[pp][0] = h0; *(float4*)&h2g[pp][4] = h1_;
      }
    }
    __syncthreads();                               // bar3: h2 published

    // D: oacc += h2 . Wog (zero-padded for cols <= i -> no branch)
    {
      float wBa[9] = {B0.x, B0.y, B0.z, B0.w, B1.x, B1.y, B1.z, B1.w, B2.x};
      float wBb[9] = {B2.z, B2.w, B3.x, B3.y, B3.z, B3.w, B4.x, B4.y, B4.z};
      #pragma unroll
      for (int p = 0; p < 9; ++p) {
        f2 h = *(const f2*)&h2g[p][2 * rp];        // b64 broadcast (wave-uniform)
        ocA += (f2){wBa[p], wBa[p]} * h;
        ocB += (f2){wBb[p], wBb[p]} * h;
      }
    }
    wq0p += 6144; wq1p += 6144; wopp += 1280;
  }

  // ---- epilogue: thread (rp,l) holds z/mu/sc for rows 2rp,2rp+1 col l ----
  out[(b0 + 2 * rp) * Dn + l] = zs.x;
  out[(b0 + 2 * rp + 1) * Dn + l] = zs.y;
  out[Bn * Dn + (b0 + 2 * rp) * Dn + l] = mus.x;
  out[Bn * Dn + (b0 + 2 * rp + 1) * Dn + l] = mus.y;
  out[2 * Bn * Dn + (b0 + 2 * rp) * Dn + l] = scs.x;
  out[2 * Bn * Dn + (b0 + 2 * rp + 1) * Dn + l] = scs.y;
}

extern "C" void kernel_launch(void* const* d_in, const int* in_sizes, int n_in,
                              void* d_out, int out_size, void* d_ws, size_t ws_size,
                              hipStream_t stream) {
  const float* context = (const float*)d_in[0];
  const float* eps     = (const float*)d_in[1];
  const float* W1      = (const float*)d_in[2];
  const float* b1      = (const float*)d_in[3];
  const float* Wc      = (const float*)d_in[4];
  const float* W2      = (const float*)d_in[5];
  const float* b2      = (const float*)d_in[6];
  const float* Wo      = (const float*)d_in[7];
  const float* bo      = (const float*)d_in[8];
  float* out = (float*)d_out;

  float* ws   = (float*)d_ws;
  float* Wq   = ws;                        // 393216 floats
  float* Woq  = Wq + WQ_SZ;                //  81920
  float* WcpT = Woq + WOQ_SZ;              // 131072
  float* b1p  = WcpT + WCP_SZ;             //    512
  float* b2p  = b1p + 512;                 //    512
  // total ws use: ~2.4 MB (L2-resident)

  int prep_elems = WQ_SZ + WOQ_SZ + WCP_SZ + 1024;
  prep_kernel<<<(prep_elems + 255) / 256, 256, 0, stream>>>(
      W1, Wc, W2, Wo, b1, b2, Wq, Woq, WcpT, b1p, b2p);
  made_pk_kernel<<<Bn / Rn, 256, 0, stream>>>(context, WcpT, b1p, Wq, Woq,
                                              b2p, bo, eps, out);
}

// Round 13
// 237.693 us; speedup vs baseline: 1.1529x; 1.1529x over previous
//
#include <hip/hip_runtime.h>
#include <math.h>

// MADE autoregressive sampler, incremental-by-degree, v12.
// B=8192, D=64, CTX=256, H=512. Units sorted by degree (mh = h%63+1).
// Hot kernel: byte-identical to v9 (best measured: 187 us, occ 37%,
// launch_bounds(256,4); the 64-VGPR clamp costs only a one-time ~2B/thread
// prologue spill, far cheaper than (256,2)'s occupancy loss -- v11 evidence).
// v12 change: prep rewritten scan-order -- every global READ is coalesced
// (thread = source element; scattered stores are fire-and-forget). Zero-masks
// dropped where the destination accumulator is provably never re-read
// (dead-unit a1/a2, post-sample oacc); only Wq/Woq slot-8 for i>=8 needs
// explicit zeroing (read against stale h1g/h2g by the 9-wide inner loop).

typedef float f2 __attribute__((ext_vector_type(2)));

#define Bn 8192
#define Dn 64
#define CTXn 256
#define Hn 512
#define On 128
#define Rn 8

#define WQ_SZ  (64 * 512 * 12)   // 393216
#define WOQ_SZ (64 * 64 * 20)    //  81920
#define WCP_SZ (CTXn * Hn)       // 131072

// sorted index p -> original hidden unit h, and its degree k.
__device__ __forceinline__ int perm_of(int p, int* degout) {
  int k, t;
  if (p < 72) { k = p / 9 + 1; t = p - (k - 1) * 9; }
  else        { int pp = p - 72; k = pp / 8 + 9; t = pp - (k - 9) * 8; }
  *degout = k;
  return (k - 1) + 63 * t;
}
// original unit h -> sorted index q.
__device__ __forceinline__ int inv_perm(int h) {
  int i = h % 63;            // = degree-1
  int t = h / 63;
  int base = (i < 9) ? 9 * i : 72 + 8 * (i - 8);   // S_of(i+1)
  return base + t;
}

// ---------------- prep: scan-order, coalesced reads -------------------------
// R0 W2-scan:  W2[hq][hp], hp=63e+i -> Wq[i][qs(hq)][e]
// R1 W1-scan:  W1[hq][i]            -> Wq[i][qs(hq)][9]
// R2 Wo-scan:  Wo[o][hp], hp=63p+i  -> Woq[i][o&63][(o>>6)*10+p]
// R3 Wc-scan:  Wc[hq][cc]           -> WcpT[cc][qs(hq)]
// R4 zero:     Wq[i>=8][q][8], Woq[i>=8][j][8|18]  (9-wide loop pads)
// R5 biases:   b1p/b2p (512 each, scattered reads, negligible)
#define R0e 262144
#define R1e (R0e + 32768)
#define R2e (R1e + 65536)
#define R3e (R2e + 131072)
#define R4e (R3e + 35840)
#define R5e (R4e + 1024)
__global__ void prep_kernel(const float* __restrict__ W1, const float* __restrict__ Wc,
                            const float* __restrict__ W2, const float* __restrict__ Wo,
                            const float* __restrict__ b1, const float* __restrict__ b2,
                            float* __restrict__ Wq, float* __restrict__ Woq,
                            float* __restrict__ WcpT, float* __restrict__ b1p,
                            float* __restrict__ b2p) {
  int idx = blockIdx.x * 256 + threadIdx.x;
  if (idx < R0e) {                      // W2 scan (coalesced read)
    int hq = idx >> 9, hp = idx & 511;
    int i = hp % 63, e = hp / 63;       // group i, slot e (< c by construction)
    Wq[i * 6144 + inv_perm(hq) * 12 + e] = W2[idx];
  } else if (idx < R1e) {               // W1 scan
    int jj = idx - R0e;
    int hq = jj >> 6, i = jj & 63;
    Wq[i * 6144 + inv_perm(hq) * 12 + 9] = W1[jj];
  } else if (idx < R2e) {               // Wo scan
    int jj = idx - R1e;
    int o = jj >> 9, hp = jj & 511;
    int i = hp % 63, p = hp / 63;
    int j = o & 63, half = o >> 6;
    Woq[i * 1280 + j * 20 + half * 10 + p] = Wo[jj];
  } else if (idx < R3e) {               // Wc scan
    int jj = idx - R2e;
    int hq = jj >> 8, cc = jj & 255;
    WcpT[cc * 512 + inv_perm(hq)] = Wc[jj];
  } else if (idx < R4e) {               // zero the 9th slots for 8-wide groups
    int z = idx - R3e;
    if (z < 28672) {                    // Wq[i][q][8], i = 8..63
      int i = 8 + (z >> 9), q = z & 511;
      Wq[i * 6144 + q * 12 + 8] = 0.f;
    } else {                            // Woq[i][j][8 or 18], i = 8..63
      int z2 = z - 28672;
      int i = 8 + (z2 >> 7), r = z2 & 127;
      int j = r & 63, half = r >> 6;
      Woq[i * 1280 + j * 20 + half * 10 + 8] = 0.f;
    }
  } else if (idx < R5e) {               // permuted biases
    int z = idx - R4e;
    if (z < 512) {
      int dq; int hq = perm_of(z, &dq);
      b1p[z] = b1[hq];
    } else {
      int q = z - 512;
      int dq; int hq = perm_of(q, &dq);
      b2p[q] = b2[hq];
    }
  }
}

// ---------------- main fused kernel (byte-identical to v9) -------------------
__global__ __launch_bounds__(256, 4)
void made_pk_kernel(
    const float* __restrict__ context, const float* __restrict__ WcpT,
    const float* __restrict__ b1p,
    const float* __restrict__ Wq, const float* __restrict__ Woq,
    const float* __restrict__ b2p, const float* __restrict__ bo,
    const float* __restrict__ eps, float* __restrict__ out) {
  __shared__ __align__(16) float ctxR[8][264];
  __shared__ __align__(16) float zcur[8];
  __shared__ __align__(16) float h1g[9][8];
  __shared__ __align__(16) float h2g[9][8];

  int t = threadIdx.x;
  int b0 = blockIdx.x * Rn;
  int rp = t >> 6, l = t & 63;           // wave rp owns rows 2rp, 2rp+1; col-pair l
  int q0 = t, q1 = t + 256;              // owned sorted units

  int g0 = ((q0 < 72) ? q0 / 9 + 1 : (q0 - 72) / 8 + 9) - 1;   // finalize steps
  int g1 = ((q1 - 72) / 8 + 9) - 1;
  int qm = t | 63;                        // wave-uniform max index
  int gm0s = __builtin_amdgcn_readfirstlane(
      ((qm < 72) ? qm / 9 + 1 : (qm - 72) / 8 + 9) - 1);
  int gm1s = __builtin_amdgcn_readfirstlane(((qm + 256 - 72) / 8 + 9) - 1);

  // ---- stage ctx ----
  #pragma unroll
  for (int r = 0; r < 8; ++r)
    ctxR[r][t] = context[(b0 + r) * CTXn + t];
  __syncthreads();

  // ---- ctx GEMM ----
  float acc0[8], acc1[8];
  {
    float bias0 = b1p[q0], bias1 = b1p[q1];
    #pragma unroll
    for (int r = 0; r < 8; ++r) { acc0[r] = bias0; acc1[r] = bias1; }
  }
  {
    const float* wc = WcpT;
    #pragma clang loop unroll(disable)
    for (int c4 = 0; c4 < CTXn / 4; ++c4) {
      float xr[8][4];
      #pragma unroll
      for (int r = 0; r < 8; ++r) {
        float4 x = *(const float4*)&ctxR[r][4 * c4];
        xr[r][0] = x.x; xr[r][1] = x.y; xr[r][2] = x.z; xr[r][3] = x.w;
      }
      #pragma unroll
      for (int k = 0; k < 4; ++k) {
        float w0 = wc[q0], w1 = wc[q1];
        #pragma unroll
        for (int r = 0; r < 8; ++r) {
          acc0[r] = fmaf(xr[r][k], w0, acc0[r]);
          acc1[r] = fmaf(xr[r][k], w1, acc1[r]);
        }
        wc += Hn;
      }
    }
  }

  // ---- pack state into float2 row-pairs ----
  f2 a10[4], a11[4], a20[4], a21[4];
  #pragma unroll
  for (int r2 = 0; r2 < 4; ++r2) {
    a10[r2] = (f2){acc0[2 * r2], acc0[2 * r2 + 1]};
    a11[r2] = (f2){acc1[2 * r2], acc1[2 * r2 + 1]};
  }
  {
    float bb0 = b2p[q0], bb1 = b2p[q1];
    #pragma unroll
    for (int r2 = 0; r2 < 4; ++r2) {
      a20[r2] = (f2){bb0, bb0};
      a21[r2] = (f2){bb1, bb1};
    }
  }
  f2 ocA = (f2){bo[l], bo[l]};           // col l, rows (2rp, 2rp+1)
  f2 ocB = (f2){bo[l + 64], bo[l + 64]};
  f2 ez2 = (f2){eps[(b0 + 2 * rp) * Dn + l], eps[(b0 + 2 * rp + 1) * Dn + l]};
  f2 zs = (f2){0.f, 0.f}, mus = zs, scs = zs;

  const float* wq0p = Wq + (size_t)q0 * 12;
  const float* wq1p = Wq + (size_t)q1 * 12;
  const float* wopp = Woq + (size_t)l * 20;

  // ---- sequential loop: 3 barriers/step (must stay rolled) ----
  #pragma clang loop unroll(disable)
  for (int i = 0; i < Dn; ++i) {
    // E: this thread's cols (l, l+64) final when l == i (oacc through D(i-1))
    if (l == i) {
      f2 pre = ocB;
      float sx = fmaxf(pre.x, 0.f) + __logf(1.f + __expf(-fabsf(pre.x)));
      float sy = fmaxf(pre.y, 0.f) + __logf(1.f + __expf(-fabsf(pre.y)));
      f2 sc = (f2){sx, sy};
      f2 z = ocA + sc * ez2;
      *(f2*)&zcur[2 * rp] = z;
      zs = z; mus = ocA; scs = sc;
    }
    __syncthreads();                               // bar1: z published

    int sb = (i < 8) ? 9 * i : 8 * i + 8;          // group-i base
    bool liveB = (i <= gm1s);                      // wave-uniform
    bool liveA = (i <= gm0s);
    float4 A1c0, A1c1, A1c2, A0c0, A0c1, A0c2;
    if (liveB) {
      const float4* a4 = (const float4*)wq1p;      // 3 b128, imm offsets
      A1c0 = a4[0]; A1c1 = a4[1]; A1c2 = a4[2];
      if (liveA) {
        const float4* b4 = (const float4*)wq0p;
        A0c0 = b4[0]; A0c1 = b4[1]; A0c2 = b4[2];
      }
      float4 za = *(const float4*)&zcur[0];
      float4 zb = *(const float4*)&zcur[4];
      f2 zc0 = (f2){za.x, za.y}, zc1 = (f2){za.z, za.w};
      f2 zc2 = (f2){zb.x, zb.y}, zc3 = (f2){zb.z, zb.w};
      // FA unit1: a1 += z_i * W1 (slot [9] = chunk2.y), publish if finalizing
      {
        f2 wv = (f2){A1c2.y, A1c2.y};
        a11[0] += wv * zc0; a11[1] += wv * zc1;
        a11[2] += wv * zc2; a11[3] += wv * zc3;
        if (g1 == i) {
          int pp = q1 - sb;
          float4 h0 = {fmaxf(a11[0].x, 0.f), fmaxf(a11[0].y, 0.f),
                       fmaxf(a11[1].x, 0.f), fmaxf(a11[1].y, 0.f)};
          float4 h1_ = {fmaxf(a11[2].x, 0.f), fmaxf(a11[2].y, 0.f),
                        fmaxf(a11[3].x, 0.f), fmaxf(a11[3].y, 0.f)};
          *(float4*)&h1g[pp][0] = h0; *(float4*)&h1g[pp][4] = h1_;
        }
      }
      if (liveA) {
        f2 wv = (f2){A0c2.y, A0c2.y};
        a10[0] += wv * zc0; a10[1] += wv * zc1;
        a10[2] += wv * zc2; a10[3] += wv * zc3;
        if (g0 == i) {
          int pp = q0 - sb;
          float4 h0 = {fmaxf(a10[0].x, 0.f), fmaxf(a10[0].y, 0.f),
                       fmaxf(a10[1].x, 0.f), fmaxf(a10[1].y, 0.f)};
          float4 h1_ = {fmaxf(a10[2].x, 0.f), fmaxf(a10[2].y, 0.f),
                        fmaxf(a10[3].x, 0.f), fmaxf(a10[3].y, 0.f)};
          *(float4*)&h1g[pp][0] = h0; *(float4*)&h1g[pp][4] = h1_;
        }
      }
    }
    __syncthreads();                               // bar2: h1 published

    // Woq prefetch (used in D after bar3 -> drains at an anyway-barrier)
    const float4* w4 = (const float4*)wopp;
    float4 B0 = w4[0], B1 = w4[1], B2 = w4[2], B3 = w4[3], B4 = w4[4];

    if (liveB) {
      float wA1[9] = {A1c0.x, A1c0.y, A1c0.z, A1c0.w,
                      A1c1.x, A1c1.y, A1c1.z, A1c1.w, A1c2.x};
      if (liveA) {
        float wA0[9] = {A0c0.x, A0c0.y, A0c0.z, A0c0.w,
                        A0c1.x, A0c1.y, A0c1.z, A0c1.w, A0c2.x};
        #pragma unroll
        for (int p = 0; p < 9; ++p) {
          float4 ha = *(const float4*)&h1g[p][0];
          float4 hb = *(const float4*)&h1g[p][4];
          f2 h0 = (f2){ha.x, ha.y}, h1_ = (f2){ha.z, ha.w};
          f2 h2_ = (f2){hb.x, hb.y}, h3 = (f2){hb.z, hb.w};
          f2 wv1 = (f2){wA1[p], wA1[p]};
          f2 wv0 = (f2){wA0[p], wA0[p]};
          a21[0] += wv1 * h0; a21[1] += wv1 * h1_;
          a21[2] += wv1 * h2_; a21[3] += wv1 * h3;
          a20[0] += wv0 * h0; a20[1] += wv0 * h1_;
          a20[2] += wv0 * h2_; a20[3] += wv0 * h3;
        }
      } else {
        #pragma unroll
        for (int p = 0; p < 9; ++p) {
          float4 ha = *(const float4*)&h1g[p][0];
          float4 hb = *(const float4*)&h1g[p][4];
          f2 h0 = (f2){ha.x, ha.y}, h1_ = (f2){ha.z, ha.w};
          f2 h2_ = (f2){hb.x, hb.y}, h3 = (f2){hb.z, hb.w};
          f2 wv1 = (f2){wA1[p], wA1[p]};
          a21[0] += wv1 * h0; a21[1] += wv1 * h1_;
          a21[2] += wv1 * h2_; a21[3] += wv1 * h3;
        }
      }
      if (g1 == i) {
        int pp = q1 - sb;
        float4 h0 = {fmaxf(a21[0].x, 0.f), fmaxf(a21[0].y, 0.f),
                     fmaxf(a21[1].x, 0.f), fmaxf(a21[1].y, 0.f)};
        float4 h1_ = {fmaxf(a21[2].x, 0.f), fmaxf(a21[2].y, 0.f),
                      fmaxf(a21[3].x, 0.f), fmaxf(a21[3].y, 0.f)};
        *(float4*)&h2g[pp][0] = h0; *(float4*)&h2g[pp][4] = h1_;
      }
      if (liveA && g0 == i) {
        int pp = q0 - sb;
        float4 h0 = {fmaxf(a20[0].x, 0.f), fmaxf(a20[0].y, 0.f),
                     fmaxf(a20[1].x, 0.f), fmaxf(a20[1].y, 0.f)};
        float4 h1_ = {fmaxf(a20[2].x, 0.f), fmaxf(a20[2].y, 0.f),
                      fmaxf(a20[3].x, 0.f), fmaxf(a20[3].y, 0.f)};
        *(float4*)&h2g[pp][0] = h0; *(float4*)&h2g[pp][4] = h1_;
      }
    }
    __syncthreads();                               // bar3: h2 published

    // D: oacc += h2 . Wog (slot-8 zeroed in prep; j<=i garbage lands in
    // already-consumed oacc -> harmless)
    {
      float wBa[9] = {B0.x, B0.y, B0.z, B0.w, B1.x, B1.y, B1.z, B1.w, B2.x};
      float wBb[9] = {B2.z, B2.w, B3.x, B3.y, B3.z, B3.w, B4.x, B4.y, B4.z};
      #pragma unroll
      for (int p = 0; p < 9; ++p) {
        f2 h = *(const f2*)&h2g[p][2 * rp];        // b64 broadcast (wave-uniform)
        ocA += (f2){wBa[p], wBa[p]} * h;
        ocB += (f2){wBb[p], wBb[p]} * h;
      }
    }
    wq0p += 6144; wq1p += 6144; wopp += 1280;
  }

  // ---- epilogue: thread (rp,l) holds z/mu/sc for rows 2rp,2rp+1 col l ----
  out[(b0 + 2 * rp) * Dn + l] = zs.x;
  out[(b0 + 2 * rp + 1) * Dn + l] = zs.y;
  out[Bn * Dn + (b0 + 2 * rp) * Dn + l] = mus.x;
  out[Bn * Dn + (b0 + 2 * rp + 1) * Dn + l] = mus.y;
  out[2 * Bn * Dn + (b0 + 2 * rp) * Dn + l] = scs.x;
  out[2 * Bn * Dn + (b0 + 2 * rp + 1) * Dn + l] = scs.y;
}

extern "C" void kernel_launch(void* const* d_in, const int* in_sizes, int n_in,
                              void* d_out, int out_size, void* d_ws, size_t ws_size,
                              hipStream_t stream) {
  const float* context = (const float*)d_in[0];
  const float* eps     = (const float*)d_in[1];
  const float* W1      = (const float*)d_in[2];
  const float* b1      = (const float*)d_in[3];
  const float* Wc      = (const float*)d_in[4];
  const float* W2      = (const float*)d_in[5];
  const float* b2      = (const float*)d_in[6];
  const float* Wo      = (const float*)d_in[7];
  const float* bo      = (const float*)d_in[8];
  float* out = (float*)d_out;

  float* ws   = (float*)d_ws;
  float* Wq   = ws;                        // 393216 floats
  float* Woq  = Wq + WQ_SZ;                //  81920
  float* WcpT = Woq + WOQ_SZ;              // 131072
  float* b1p  = WcpT + WCP_SZ;             //    512
  float* b2p  = b1p + 512;                 //    512
  // total ws use: ~2.4 MB (L2-resident)

  prep_kernel<<<(R5e + 255) / 256, 256, 0, stream>>>(
      W1, Wc, W2, Wo, b1, b2, Wq, Woq, WcpT, b1p, b2p);
  made_pk_kernel<<<Bn / Rn, 256, 0, stream>>>(context, WcpT, b1p, Wq, Woq,
                                              b2p, bo, eps, out);
}